// Round 7
// baseline (701.922 us; speedup 1.0000x reference)
//
#include <hip/hip_runtime.h>
#include <stdint.h>

#define NSEQ 512
#define DPAIR 128
#define NN (NSEQ*NSEQ)        // 262144 positions
#define LDPAD 136             // 128 + 8 pad: keeps 16B ds alignment, ~2-way conflicts max

typedef unsigned short u16;
typedef __attribute__((ext_vector_type(8))) short bf16x8;   // 8 bf16 = 4 VGPRs
typedef __attribute__((ext_vector_type(4))) float f32x4;

__device__ __forceinline__ float bf2f(u16 h){ return __uint_as_float(((uint32_t)h)<<16); }
__device__ __forceinline__ u16 f2bf(float f){
  uint32_t u = __float_as_uint(f);
  u += 0x7fffu + ((u>>16)&1u);          // RNE
  return (u16)(u>>16);
}
// HW packed f32->bf16 (RNE), 1 VALU op per 2 elements; bit-identical to f2bf for finite inputs
__device__ __forceinline__ uint32_t cvtpk(float lo, float hi){
  uint32_t r;
  asm("v_cvt_pk_bf16_f32 %0, %1, %2" : "=v"(r) : "v"(lo), "v"(hi));
  return r;
}
__device__ __forceinline__ float sigmoidf_(float x){ return 1.0f/(1.0f+__expf(-x)); }

// load one B-fragment (8 bf16 of row `row`, k-offset `k8`*8) directly from f32 weights (L2-hot)
__device__ __forceinline__ bf16x8 ldw(const float* __restrict__ w, int row, int koff){
  const float* p = w + (size_t)row*DPAIR + koff;
  float4 w0 = *(const float4*)p;
  float4 w1 = *(const float4*)(p+4);
  union { uint32_t u[4]; bf16x8 v; } bu;
  bu.u[0] = cvtpk(w0.x, w0.y);
  bu.u[1] = cvtpk(w0.z, w0.w);
  bu.u[2] = cvtpk(w1.x, w1.y);
  bu.u[3] = cvtpk(w1.z, w1.w);
  return bu.v;
}

// K1: z in LDS; ALL weight fragments loaded global->reg (no LDS staging, 3 barriers total)
// LDS = zr(17.4K) + misc ~1.2K -> 8 blocks/CU possible (thread-capped)
__global__ __launch_bounds__(256) void k1_proj(
    const float* __restrict__ z, const float* __restrict__ mask,
    const float* __restrict__ w_ab_p, const float* __restrict__ b_ab_p,
    const float* __restrict__ w_ab_g, const float* __restrict__ b_ab_g,
    const float* __restrict__ w_g, const float* __restrict__ b_g,
    const float* __restrict__ ln_g, const float* __restrict__ ln_b,
    u16* __restrict__ a_t, u16* __restrict__ b_t, u16* __restrict__ g_out)
{
  __shared__ u16 zr[64*LDPAD];     // z tile, bf16 (raw, then LN'd in place)
  __shared__ float lng[DPAIR], lnb[DPAIR], msk[64];

  const int t = threadIdx.x;
  const int p0 = blockIdx.x * 64;
  const int lane = t & 63, wv = t >> 6;
  const int wm = (wv >> 1) * 32, wn = (wv & 1) * 32;
  const int fr = lane & 15, fq = lane >> 4;
  const int koff = fq*8;           // this lane's k-offset within a 32-wide k-step

  if (t < DPAIR){ lng[t] = ln_g[t]; lnb[t] = ln_b[t]; }
  else if (t < DPAIR + 64) msk[t - DPAIR] = mask[p0 + t - DPAIR];

  { // stage raw z tile (64 pos x 128 ch, contiguous) -> bf16
    const float4* zs = (const float4*)(z + (size_t)p0 * DPAIR);
    #pragma unroll
    for (int i=0;i<8;i++){
      int e4 = i*256 + t; int pos = e4>>5, c4 = e4&31;
      float4 v = zs[e4];
      uint2 pk;
      pk.x = cvtpk(v.x, v.y);
      pk.y = cvtpk(v.z, v.w);
      *(uint2*)&zr[pos*LDPAD + c4*4] = pk;
    }
  }
  __syncthreads();

  // gate g = sigmoid(z @ w_g^T + b_g) in two 64-column halves, raw-z input, weights from global
  #pragma unroll
  for (int h=0; h<2; h++){
    f32x4 acc[2][2] = {};
    #pragma unroll
    for (int kk=0;kk<4;kk++){
      bf16x8 aF[2];
      #pragma unroll
      for (int mi=0;mi<2;mi++) aF[mi] = *(const bf16x8*)&zr[(wm+mi*16+fr)*LDPAD + kk*32 + koff];
      #pragma unroll
      for (int ni=0;ni<2;ni++){
        bf16x8 bF = ldw(w_g, h*64 + wn + ni*16 + fr, kk*32 + koff);
        #pragma unroll
        for (int mi=0;mi<2;mi++)
          acc[mi][ni] = __builtin_amdgcn_mfma_f32_16x16x32_bf16(aF[mi], bF, acc[mi][ni], 0, 0, 0);
      }
    }
    #pragma unroll
    for (int mi=0;mi<2;mi++)
      #pragma unroll
      for (int ni=0;ni<2;ni++){
        int ng = h*64 + wn + ni*16 + fr;
        float bg = b_g[ng];
        #pragma unroll
        for (int r=0;r<4;r++){
          int pos = wm + mi*16 + fq*4 + r;
          g_out[(size_t)(p0+pos)*DPAIR + ng] = f2bf(sigmoidf_(acc[mi][ni][r] + bg));
        }
      }
  }
  __syncthreads();   // all gate reads of zr complete before LN overwrites

  { // layernorm in place on zr ; 4 threads per position
    int pos = t>>2, q = t&3;
    float s=0.f, s2=0.f;
    #pragma unroll
    for (int j=0;j<32;j++){ float v = bf2f(zr[pos*LDPAD + q*32 + j]); s += v; s2 += v*v; }
    s  += __shfl_xor(s, 1);  s2 += __shfl_xor(s2, 1);
    s  += __shfl_xor(s, 2);  s2 += __shfl_xor(s2, 2);
    float mu  = s * (1.f/128.f);
    float var = s2 * (1.f/128.f) - mu*mu;
    float rs  = rsqrtf(var + 1e-5f);
    #pragma unroll
    for (int j=0;j<32;j++){
      int c = q*32 + j;
      float v = bf2f(zr[pos*LDPAD + c]);
      zr[pos*LDPAD + c] = f2bf((v - mu)*rs*lng[c] + lnb[c]);
    }
  }
  __syncthreads();

  // a/b: 4 n-tiles of 64 (nt 0,1 -> a ; 2,3 -> b); P,G weights direct global->reg; NO barriers
  for (int nt=0; nt<4; nt++){
    f32x4 accP[2][2] = {}, accG[2][2] = {};
    #pragma unroll
    for (int kk=0;kk<4;kk++){
      bf16x8 aF[2];
      #pragma unroll
      for (int mi=0;mi<2;mi++) aF[mi] = *(const bf16x8*)&zr[(wm+mi*16+fr)*LDPAD + kk*32 + koff];
      #pragma unroll
      for (int ni=0;ni<2;ni++){
        int row = nt*64 + wn + ni*16 + fr;
        bf16x8 bP = ldw(w_ab_p, row, kk*32 + koff);
        bf16x8 bG = ldw(w_ab_g, row, kk*32 + koff);
        #pragma unroll
        for (int mi=0;mi<2;mi++){
          accP[mi][ni] = __builtin_amdgcn_mfma_f32_16x16x32_bf16(aF[mi], bP, accP[mi][ni], 0, 0, 0);
          accG[mi][ni] = __builtin_amdgcn_mfma_f32_16x16x32_bf16(aF[mi], bG, accG[mi][ni], 0, 0, 0);
        }
      }
    }
    // epilogue: p*sigmoid(g)*mask, direct d-major 8B stores
    u16* dst = (nt < 2) ? a_t : b_t;
    int dbase = (nt & 1) * 64;
    #pragma unroll
    for (int mi=0;mi<2;mi++){
      int posb = wm + mi*16 + fq*4;
      #pragma unroll
      for (int ni=0;ni<2;ni++){
        int nl   = wn + ni*16 + fr;
        int ng   = nt*64 + nl;
        int drow = dbase + nl;
        float bp  = b_ab_p[ng];
        float bgv = b_ab_g[ng];
        float v0 = (accP[mi][ni][0]+bp) * sigmoidf_(accG[mi][ni][0]+bgv) * msk[posb+0];
        float v1 = (accP[mi][ni][1]+bp) * sigmoidf_(accG[mi][ni][1]+bgv) * msk[posb+1];
        float v2 = (accP[mi][ni][2]+bp) * sigmoidf_(accG[mi][ni][2]+bgv) * msk[posb+2];
        float v3 = (accP[mi][ni][3]+bp) * sigmoidf_(accG[mi][ni][3]+bgv) * msk[posb+3];
        uint2 pk;
        pk.x = cvtpk(v0, v1);
        pk.y = cvtpk(v2, v3);
        *(uint2*)&dst[(size_t)drow*NN + p0 + posb] = pk;
      }
    }
  }
}

// K2: x[i,j,d] = sum_k a[i,k,d]*b[j,k,d] -> 128 GEMMs (512^3) C = A*B^T, both k-contiguous
__global__ __launch_bounds__(256) void k2_einsum(
    const u16* __restrict__ a_t, const u16* __restrict__ b_t, u16* __restrict__ x_t)
{
  __shared__ u16 As[128*40];   // 128 rows x (32 k + 8 pad)
  __shared__ u16 Bs[128*40];
  const int t = threadIdx.x;
  const int d  = blockIdx.z;
  const int i0 = blockIdx.x * 128;
  const int j0 = blockIdx.y * 128;
  const u16* Ag = a_t + (size_t)d*NN + (size_t)i0*NSEQ;
  const u16* Bg = b_t + (size_t)d*NN + (size_t)j0*NSEQ;

  const int lane = t & 63, wv = t >> 6;
  const int wm = (wv >> 1) * 64, wn = (wv & 1) * 64;
  const int fr = lane & 15, fq = lane >> 4;

  f32x4 acc[4][4] = {};

  for (int k0 = 0; k0 < NSEQ; k0 += 32){
    __syncthreads();
    #pragma unroll
    for (int i=0;i<2;i++){
      int e = i*256 + t; int r = e>>2, c8 = e&3;
      uint4 va = *(const uint4*)(Ag + (size_t)r*NSEQ + k0 + c8*8);
      *(uint4*)&As[r*40 + c8*8] = va;
      uint4 vb = *(const uint4*)(Bg + (size_t)r*NSEQ + k0 + c8*8);
      *(uint4*)&Bs[r*40 + c8*8] = vb;
    }
    __syncthreads();
    bf16x8 aF[4], bF[4];
    #pragma unroll
    for (int mi=0;mi<4;mi++) aF[mi] = *(const bf16x8*)&As[(wm + mi*16 + fr)*40 + fq*8];
    #pragma unroll
    for (int ni=0;ni<4;ni++) bF[ni] = *(const bf16x8*)&Bs[(wn + ni*16 + fr)*40 + fq*8];
    #pragma unroll
    for (int mi=0;mi<4;mi++)
      #pragma unroll
      for (int ni=0;ni<4;ni++)
        acc[mi][ni] = __builtin_amdgcn_mfma_f32_16x16x32_bf16(aF[mi], bF[ni], acc[mi][ni], 0, 0, 0);
  }
  u16* Xg = x_t + (size_t)d*NN;
  #pragma unroll
  for (int mi=0;mi<4;mi++)
    #pragma unroll
    for (int ni=0;ni<4;ni++)
      #pragma unroll
      for (int r=0;r<4;r++){
        int row = i0 + wm + mi*16 + fq*4 + r;
        int col = j0 + wn + ni*16 + fr;
        Xg[(size_t)row*NSEQ + col] = f2bf(acc[mi][ni][r]);
      }
}

// K3: out = g * (LN(x) @ w_z^T + b_z), fp32 out
__global__ __launch_bounds__(256) void k3_out(
    const u16* __restrict__ x_t, const u16* __restrict__ g_in,
    const float* __restrict__ w_z, const float* __restrict__ b_z,
    const float* __restrict__ ln_g, const float* __restrict__ ln_b,
    float* __restrict__ out)
{
  __shared__ u16 xs[64*LDPAD];      // 64 pos x 128 d
  __shared__ u16 wz[DPAIR*LDPAD];   // 128 c x 128 d
  __shared__ float lng[DPAIR], lnb[DPAIR], bzs[DPAIR];

  const int t = threadIdx.x;
  const int p0 = blockIdx.x * 64;
  if (t < DPAIR){ lng[t] = ln_g[t]; lnb[t] = ln_b[t]; bzs[t] = b_z[t]; }

  { // stage w_z -> bf16
    const float4* ws = (const float4*)w_z;
    #pragma unroll
    for (int i=0;i<16;i++){
      int e4 = i*256 + t; int r = e4>>5, c4 = e4&31;
      float4 v = ws[e4];
      uint2 pk;
      pk.x = cvtpk(v.x, v.y);
      pk.y = cvtpk(v.z, v.w);
      *(uint2*)&wz[r*LDPAD + c4*4] = pk;
    }
  }
  { // transpose-stage x: xs[pos][d] <- x_t[d][p0+pos] (coalesced 8B global reads)
    #pragma unroll
    for (int i=0;i<8;i++){
      int e = i*256 + t; int dd = e>>4, pc = e&15;
      uint2 v = *(const uint2*)(x_t + (size_t)dd*NN + p0 + pc*4);
      int pb = pc*4;
      xs[(pb+0)*LDPAD + dd] = (u16)(v.x & 0xffffu);
      xs[(pb+1)*LDPAD + dd] = (u16)(v.x >> 16);
      xs[(pb+2)*LDPAD + dd] = (u16)(v.y & 0xffffu);
      xs[(pb+3)*LDPAD + dd] = (u16)(v.y >> 16);
    }
  }
  __syncthreads();
  { // layernorm over d, in place
    int pos = t>>2, q = t&3;
    float s=0.f, s2=0.f;
    #pragma unroll
    for (int j=0;j<32;j++){ float v = bf2f(xs[pos*LDPAD + q*32 + j]); s += v; s2 += v*v; }
    s  += __shfl_xor(s, 1);  s2 += __shfl_xor(s2, 1);
    s  += __shfl_xor(s, 2);  s2 += __shfl_xor(s2, 2);
    float mu  = s * (1.f/128.f);
    float var = s2 * (1.f/128.f) - mu*mu;
    float rs  = rsqrtf(var + 1e-5f);
    #pragma unroll
    for (int j=0;j<32;j++){
      int c = q*32 + j;
      float v = bf2f(xs[pos*LDPAD + c]);
      xs[pos*LDPAD + c] = f2bf((v - mu)*rs*lng[c] + lnb[c]);
    }
  }
  __syncthreads();
  // GEMM: 64 pos x 128 c x 128 d ; wave tile 32x64
  const int lane = t & 63, wv = t >> 6;
  const int wm = (wv >> 1) * 32, wn = (wv & 1) * 64;
  const int fr = lane & 15, fq = lane >> 4;
  f32x4 acc[2][4] = {};
  #pragma unroll
  for (int kk=0;kk<4;kk++){
    bf16x8 aF[2], bF[4];
    #pragma unroll
    for (int mi=0;mi<2;mi++) aF[mi] = *(const bf16x8*)&xs[(wm+mi*16+fr)*LDPAD + kk*32 + fq*8];
    #pragma unroll
    for (int ni=0;ni<4;ni++) bF[ni] = *(const bf16x8*)&wz[(wn+ni*16+fr)*LDPAD + kk*32 + fq*8];
    #pragma unroll
    for (int mi=0;mi<2;mi++)
      #pragma unroll
      for (int ni=0;ni<4;ni++)
        acc[mi][ni] = __builtin_amdgcn_mfma_f32_16x16x32_bf16(aF[mi], bF[ni], acc[mi][ni], 0, 0, 0);
  }
  #pragma unroll
  for (int mi=0;mi<2;mi++)
    #pragma unroll
    for (int ni=0;ni<4;ni++)
      #pragma unroll
      for (int r=0;r<4;r++){
        int pos = wm + mi*16 + fq*4 + r;
        int c   = wn + ni*16 + fr;
        float gv = bf2f(g_in[(size_t)(p0+pos)*DPAIR + c]);
        out[(size_t)(p0+pos)*DPAIR + c] = gv * (acc[mi][ni][r] + bzs[c]);
      }
}

extern "C" void kernel_launch(void* const* d_in, const int* in_sizes, int n_in,
                              void* d_out, int out_size, void* d_ws, size_t ws_size,
                              hipStream_t stream)
{
  const float* z        = (const float*)d_in[0];
  const float* mask     = (const float*)d_in[1];
  const float* w_ab_p   = (const float*)d_in[2];
  const float* b_ab_p   = (const float*)d_in[3];
  const float* w_ab_g   = (const float*)d_in[4];
  const float* b_ab_g   = (const float*)d_in[5];
  const float* w_g      = (const float*)d_in[6];
  const float* b_g      = (const float*)d_in[7];
  const float* w_z      = (const float*)d_in[8];
  const float* b_z      = (const float*)d_in[9];
  const float* ln_in_g  = (const float*)d_in[10];
  const float* ln_in_b  = (const float*)d_in[11];
  const float* ln_out_g = (const float*)d_in[12];
  const float* ln_out_b = (const float*)d_in[13];
  float* out = (float*)d_out;

  const size_t plane = (size_t)DPAIR * NN;            // 33.5M elems
  if (ws_size < 4 * plane * sizeof(u16)) return;      // need 256 MB scratch

  u16* a_t = (u16*)d_ws;            // [128][512][512] bf16, a[i,k,d] -> a_t[d][i*512+k]
  u16* b_t = a_t + plane;           // same, b
  u16* g_b = b_t + plane;           // [pos][128] bf16 gate
  u16* x_t = g_b + plane;           // [128][512][512] bf16 einsum result

  k1_proj<<<dim3(NN/64), dim3(256), 0, stream>>>(
      z, mask, w_ab_p, b_ab_p, w_ab_g, b_ab_g, w_g, b_g, ln_in_g, ln_in_b, a_t, b_t, g_b);
  k2_einsum<<<dim3(4, 4, DPAIR), dim3(256), 0, stream>>>(a_t, b_t, x_t);
  k3_out<<<dim3(NN/64), dim3(256), 0, stream>>>(x_t, g_b, w_z, b_z, ln_out_g, ln_out_b, out);
}